// Round 10
// baseline (161.196 us; speedup 1.0000x reference)
//
#include <hip/hip_runtime.h>
#include <float.h>

// z: (64,32,32,64) fp32 -> N=65536 rows, D=64 ; codebook: (1024,64) fp32
// out concat fp32: zq [N*64] | tokens-as-float [N] | codebook [1024*64]
constexpr int D     = 64;
constexpr int V     = 1024;
constexpr int NROWS = 65536;
// Split-f16 screen (zh*ch + zh*cl + zl*ch); MARGIN certifies argmin.
// Same screen+margin passed with absmax=0 in rounds 4, 8, 9.
constexpr float MARGIN = 0.01f;

typedef _Float16 half8 __attribute__((ext_vector_type(8)));
typedef float    f32x4 __attribute__((ext_vector_type(4)));

// ---------------- prep: convert codebook ONCE (r7-diag-verified bit-exact) ----------------
__global__ __launch_bounds__(256) void vq_prep(
    const float* __restrict__ cb, _Float16* __restrict__ wsH,
    _Float16* __restrict__ wsL, float* __restrict__ c2,
    float* __restrict__ cbout) {
  const int t = blockIdx.x * 256 + threadIdx.x;  // grid = 4 blocks -> 1024 threads
#pragma unroll
  for (int i = 0; i < 16; ++i)   // coalesced codebook passthrough
    ((float4*)cbout)[i * 1024 + t] = ((const float4*)cb)[i * 1024 + t];

  const int cw = t;
  const float* src = cb + (size_t)cw * D;
  float part = 0.f;
#pragma unroll
  for (int chunk = 0; chunk < 8; ++chunk) {
    float4 q0 = ((const float4*)(src + chunk * 8))[0];
    float4 q1 = ((const float4*)(src + chunk * 8))[1];
    float xs[8] = {q0.x, q0.y, q0.z, q0.w, q1.x, q1.y, q1.z, q1.w};
    half8 hh, hl;
#pragma unroll
    for (int e = 0; e < 8; ++e) {
      _Float16 hi = (_Float16)xs[e];
      hh[e] = hi;
      hl[e] = (_Float16)(xs[e] - (float)hi);
      part  = fmaf(xs[e], xs[e], part);
    }
    *(half8*)&wsH[((size_t)chunk * V + cw) * 8] = hh;
    *(half8*)&wsL[((size_t)chunk * V + cw) * 8] = hl;
  }
  c2[cw] = part;
}

// ---------------- screen: r9 skeleton VERBATIM, 16x64 phases for 8 blocks/CU ----------------
// 1024 blocks x 256 threads; wave owns ONE 16-row tile (rowbase = gw*16).
// 16 phases x 64 codewords -> LDS ~17 KB -> 8 blocks/CU = 32 waves/CU (HW max;
// r9's 33 KB allowed 4 blocks/CU and measured only ~10 waves/CU resident).
// Per-element arithmetic, MFMA order, codeword visit order (vcol ascending
// 0..1023) and tie-breaks are bit-identical to r9.
__global__ __launch_bounds__(256, 8) void vq_screen(
    const float* __restrict__ z, const float* __restrict__ cb,
    const _Float16* __restrict__ wsH, const _Float16* __restrict__ wsL,
    const float* __restrict__ c2g,
    float* __restrict__ zq, float* __restrict__ tok,
    int* __restrict__ cnt, int* __restrict__ list) {
  __shared__ __align__(16) _Float16 sBh[8][64][8];   // 8 KiB
  __shared__ __align__(16) _Float16 sBl[8][64][8];   // 8 KiB
  __shared__ __align__(16) float sC2[64];
  __shared__ int   sW[4][16];
  __shared__ int   sFlagRows[64];
  __shared__ int   sFlagCnt, sFlagBase;

  const int tid  = threadIdx.x;
  const int lane = tid & 63;
  const int wv   = tid >> 6;        // wave 0..3
  const int l15  = lane & 15;
  const int quad = lane >> 4;
  const int gw   = blockIdx.x * 4 + wv;   // 0..4095
  const int rowbase = gw * 16;

  if (tid == 0) sFlagCnt = 0;

  // A fragments hi/lo: row rowbase + l15, k = quad*8 + j (+32*h)  [r4-proven code]
  half8 afh[2], afl[2];
  {
    const float* zr = z + (size_t)(rowbase + l15) * D;
#pragma unroll
    for (int h = 0; h < 2; ++h) {
      const float4* p = (const float4*)(zr + h * 32 + quad * 8);
      float4 q0 = p[0], q1 = p[1];
      float xs[8] = {q0.x, q0.y, q0.z, q0.w, q1.x, q1.y, q1.z, q1.w};
      half8 ah, al;
#pragma unroll
      for (int e = 0; e < 8; ++e) {
        _Float16 hi = (_Float16)xs[e];
        ah[e] = hi;
        al[e] = (_Float16)(xs[e] - (float)hi);
      }
      afh[h] = ah; afl[h] = al;
    }
  }

  float b1[4], b2[4]; int i1[4];
#pragma unroll
  for (int r = 0; r < 4; ++r) { b1[r] = FLT_MAX; b2[r] = FLT_MAX; i1[r] = 0; }

  for (int phase = 0; phase < 16; ++phase) {
    __syncthreads();  // previous compute done before LDS overwrite
    // ---- stage 64 codewords (hi+lo, 16 KiB): 1024 x 16B over 256 threads ----
#pragma unroll
    for (int i = 0; i < 4; ++i) {
      const int idx   = i * 256 + tid;
      const int seg   = idx >> 6;       // 0..15 (0..7 hi, 8..15 lo)
      const int off   = idx & 63;
      const int chunk = seg & 7;
      const _Float16* srcb = (seg < 8) ? wsH : wsL;
      const half8 v = *(const half8*)&srcb[((size_t)chunk * V + phase * 64 + off) * 8];
      if (seg < 8) *(half8*)&sBh[chunk][off][0] = v;
      else         *(half8*)&sBl[chunk][off][0] = v;
    }
    if (tid < 16) {
      float4 q = ((const float4*)(c2g + phase * 64))[tid];
      *(float4*)&sC2[tid * 4] = q;
    }
    __syncthreads();
    // ---- 4 col-tiles of 16 codewords each ----
#pragma unroll 2
    for (int tl = 0; tl < 4; ++tl) {
      const int cwl  = tl * 16 + l15;
      const int vcol = phase * 64 + cwl;
      const float c2v = sC2[cwl];
      half8 bh0 = *(const half8*)&sBh[quad][cwl][0];      // k = quad*8+j
      half8 bh1 = *(const half8*)&sBh[4 + quad][cwl][0];  // k = 32+quad*8+j
      half8 bl0 = *(const half8*)&sBl[quad][cwl][0];
      half8 bl1 = *(const half8*)&sBl[4 + quad][cwl][0];
      f32x4 acc = {0.f, 0.f, 0.f, 0.f};
      acc = __builtin_amdgcn_mfma_f32_16x16x32_f16(afh[0], bh0, acc, 0, 0, 0);
      acc = __builtin_amdgcn_mfma_f32_16x16x32_f16(afh[1], bh1, acc, 0, 0, 0);
      acc = __builtin_amdgcn_mfma_f32_16x16x32_f16(afh[0], bl0, acc, 0, 0, 0);
      acc = __builtin_amdgcn_mfma_f32_16x16x32_f16(afh[1], bl1, acc, 0, 0, 0);
      acc = __builtin_amdgcn_mfma_f32_16x16x32_f16(afl[0], bh0, acc, 0, 0, 0);
      acc = __builtin_amdgcn_mfma_f32_16x16x32_f16(afl[1], bh1, acc, 0, 0, 0);
#pragma unroll
      for (int r = 0; r < 4; ++r) {
        float m0 = fmaf(-2.f, acc[r], c2v);
        bool  c0 = m0 < b1[r];
        b2[r] = fminf(b2[r], fmaxf(m0, b1[r]));
        b1[r] = c0 ? m0 : b1[r];
        i1[r] = c0 ? vcol : i1[r];
      }
    }
  }

  // ---- reduce over the 16 col-lanes of each quad group (C: row=quad*4+r, col=l15) ----
#pragma unroll
  for (int r = 0; r < 4; ++r) {
    float v1 = b1[r], v2 = b2[r]; int ix = i1[r];
#pragma unroll
    for (int s = 1; s < 16; s <<= 1) {
      float ov1 = __shfl_xor(v1, s);
      float ov2 = __shfl_xor(v2, s);
      int   oix = __shfl_xor(ix, s);
      bool take = (ov1 < v1) || (ov1 == v1 && oix < ix);  // first-occurrence ties
      float worse = take ? v1 : ov1;
      v2 = fminf(fminf(v2, ov2), worse);
      v1 = take ? ov1 : v1;
      ix = take ? oix : ix;
    }
    b1[r] = v1; b2[r] = v2; i1[r] = ix;
  }

  if (l15 == 0) {
#pragma unroll
    for (int r = 0; r < 4; ++r) {
      int rl = quad * 4 + r;              // row within wave tile
      sW[wv][rl] = i1[r];
      if (b2[r] - b1[r] < MARGIN) {
        int s = atomicAdd(&sFlagCnt, 1);
        sFlagRows[s] = rowbase + rl;      // global row
      }
    }
  }
  __syncthreads();
  if (tid == 0 && sFlagCnt > 0) sFlagBase = atomicAdd(cnt, sFlagCnt);
  __syncthreads();
  if (tid < sFlagCnt) list[sFlagBase + tid] = sFlagRows[tid];

  // tokens (as float): 64 rows per block
  if (tid < 64) tok[blockIdx.x * 64 + tid] = (float)sW[tid >> 4][tid & 15];

  // zq gather: 64 rows x 16 chunks of 16B = 1024 float4 over 256 threads
#pragma unroll
  for (int i = 0; i < 4; ++i) {
    int cid = i * 256 + tid;
    int r = cid >> 4, seg = cid & 15;
    int widx = sW[r >> 4][r & 15];
    float4 val = *(const float4*)(cb + (size_t)widx * D + seg * 4);
    *(float4*)(zq + (size_t)(blockIdx.x * 64 + r) * D + seg * 4) = val;
  }
}

// ---------------- exact fp32 fallback: VERBATIM round-2 block-per-row (proven) ----------------
__global__ __launch_bounds__(256) void vq_fallback(
    const float* __restrict__ z, const float* __restrict__ cb,
    const int* __restrict__ cnt, const int* __restrict__ list,
    float* __restrict__ zq, float* __restrict__ tok) {
  __shared__ float sv[256];
  __shared__ int   si[256];
  const int t = threadIdx.x;
  const int n = cnt[0];
  for (int it = blockIdx.x; it < n; it += gridDim.x) {
    int row = __builtin_amdgcn_readfirstlane(list[it]);
    const float* zr = z + (size_t)row * D;
    float zreg[D];
#pragma unroll
    for (int i = 0; i < D / 4; ++i) {
      float4 q = ((const float4*)zr)[i];
      zreg[4 * i] = q.x; zreg[4 * i + 1] = q.y; zreg[4 * i + 2] = q.z; zreg[4 * i + 3] = q.w;
    }
    float d1 = 0.f;
#pragma unroll
    for (int i = 0; i < D; ++i) d1 = fmaf(zreg[i], zreg[i], d1);
    float best = FLT_MAX; int bidx = 0;
    for (int c = 0; c < 4; ++c) {
      int v = t + 256 * c;
      const float* cp = cb + (size_t)v * D;
      float acc = 0.f, cc = 0.f;
#pragma unroll
      for (int dd = 0; dd < D; ++dd) {
        acc = fmaf(zreg[dd], cp[dd], acc);
        cc  = fmaf(cp[dd], cp[dd], cc);
      }
      float dist = (d1 + cc) - 2.f * acc;
      if (dist < best) { best = dist; bidx = v; }
    }
    sv[t] = best; si[t] = bidx;
    __syncthreads();
    for (int s = 128; s > 0; s >>= 1) {
      if (t < s) {
        float v2 = sv[t + s]; int i2 = si[t + s];
        if (v2 < sv[t] || (v2 == sv[t] && i2 < si[t])) { sv[t] = v2; si[t] = i2; }
      }
      __syncthreads();
    }
    int win = si[0];
    if (t == 0) tok[row] = (float)win;
    if (t < 16) {
      float4 q = ((const float4*)(cb + (size_t)win * D))[t];
      ((float4*)(zq + (size_t)row * D))[t] = q;
    }
    __syncthreads();  // sv/si reused next iteration
  }
}

extern "C" void kernel_launch(void* const* d_in, const int* in_sizes, int n_in,
                              void* d_out, int out_size, void* d_ws, size_t ws_size,
                              hipStream_t stream) {
  const float* z  = (const float*)d_in[0];
  const float* cb = (const float*)d_in[1];

  float* out = (float*)d_out;
  float* zq  = out;                      // [NROWS*D]
  float* tok = out + (size_t)NROWS * D;  // [NROWS]
  float* cbo = tok + NROWS;              // [V*D]

  // ws layout (~520 KiB; r7 proved ws_size >= 856 KiB, r9 counters show ~256 MiB):
  // wsH 128K | wsL 128K | c2 4K | cnt 256B | list 256K
  char* wsb = (char*)d_ws;
  _Float16* wsH  = (_Float16*)(wsb + 0);
  _Float16* wsL  = (_Float16*)(wsb + 131072);
  float*    c2   = (float*)(wsb + 262144);
  int*      cnt  = (int*)(wsb + 266240);
  int*      list = (int*)(wsb + 266496);

  hipMemsetAsync(cnt, 0, sizeof(int), stream);
  vq_prep<<<V / 256, 256, 0, stream>>>(cb, wsH, wsL, c2, cbo);
  vq_screen<<<1024, 256, 0, stream>>>(z, cb, wsH, wsL, c2, zq, tok, cnt, list);
  vq_fallback<<<1024, 256, 0, stream>>>(z, cb, cnt, list, zq, tok);
}

// Round 11
// 134.439 us; speedup vs baseline: 1.1990x; 1.1990x over previous
//
#include <hip/hip_runtime.h>
#include <float.h>

// z: (64,32,32,64) fp32 -> N=65536 rows, D=64 ; codebook: (1024,64) fp32
// out concat fp32: zq [N*64] | tokens-as-float [N] | codebook [1024*64]
constexpr int D     = 64;
constexpr int V     = 1024;
constexpr int NROWS = 65536;
// Split-f16 screen (zh*ch + zh*cl + zl*ch); MARGIN certifies argmin.
// Same screen+margin passed with absmax=0 in rounds 4, 8, 9, 10.
constexpr float MARGIN = 0.01f;

typedef _Float16 half8 __attribute__((ext_vector_type(8)));
typedef float    f32x4 __attribute__((ext_vector_type(4)));

// ---------------- prep: convert codebook ONCE (r7-diag-verified bit-exact) ----------------
__global__ __launch_bounds__(256) void vq_prep(
    const float* __restrict__ cb, _Float16* __restrict__ wsH,
    _Float16* __restrict__ wsL, float* __restrict__ c2,
    float* __restrict__ cbout) {
  const int t = blockIdx.x * 256 + threadIdx.x;  // grid = 4 blocks -> 1024 threads
#pragma unroll
  for (int i = 0; i < 16; ++i)   // coalesced codebook passthrough
    ((float4*)cbout)[i * 1024 + t] = ((const float4*)cb)[i * 1024 + t];

  const int cw = t;
  const float* src = cb + (size_t)cw * D;
  float part = 0.f;
#pragma unroll
  for (int chunk = 0; chunk < 8; ++chunk) {
    float4 q0 = ((const float4*)(src + chunk * 8))[0];
    float4 q1 = ((const float4*)(src + chunk * 8))[1];
    float xs[8] = {q0.x, q0.y, q0.z, q0.w, q1.x, q1.y, q1.z, q1.w};
    half8 hh, hl;
#pragma unroll
    for (int e = 0; e < 8; ++e) {
      _Float16 hi = (_Float16)xs[e];
      hh[e] = hi;
      hl[e] = (_Float16)(xs[e] - (float)hi);
      part  = fmaf(xs[e], xs[e], part);
    }
    *(half8*)&wsH[((size_t)chunk * V + cw) * 8] = hh;
    *(half8*)&wsL[((size_t)chunk * V + cw) * 8] = hl;
  }
  c2[cw] = part;
}

// ---------------- screen: r10 source VERBATIM except launch bounds ----------------
// r10's (256,8) capped VGPR at 64 -> allocator spilled (VGPR 32, +26.7 MB
// scratch writes, 75 us). (256,6) caps at 85 >= the 52 this kernel needs:
// 6 blocks/CU (LDS 17 KB x 6 = 102 KB), 24 waves/CU, NO spill.
// Math/visit order bit-identical to r9/r10 (both passed absmax=0).
__global__ __launch_bounds__(256, 6) void vq_screen(
    const float* __restrict__ z, const float* __restrict__ cb,
    const _Float16* __restrict__ wsH, const _Float16* __restrict__ wsL,
    const float* __restrict__ c2g,
    float* __restrict__ zq, float* __restrict__ tok,
    int* __restrict__ cnt, int* __restrict__ list) {
  __shared__ __align__(16) _Float16 sBh[8][64][8];   // 8 KiB
  __shared__ __align__(16) _Float16 sBl[8][64][8];   // 8 KiB
  __shared__ __align__(16) float sC2[64];
  __shared__ int   sW[4][16];
  __shared__ int   sFlagRows[64];
  __shared__ int   sFlagCnt, sFlagBase;

  const int tid  = threadIdx.x;
  const int lane = tid & 63;
  const int wv   = tid >> 6;        // wave 0..3
  const int l15  = lane & 15;
  const int quad = lane >> 4;
  const int gw   = blockIdx.x * 4 + wv;   // 0..4095
  const int rowbase = gw * 16;

  if (tid == 0) sFlagCnt = 0;

  // A fragments hi/lo: row rowbase + l15, k = quad*8 + j (+32*h)  [r4-proven code]
  half8 afh[2], afl[2];
  {
    const float* zr = z + (size_t)(rowbase + l15) * D;
#pragma unroll
    for (int h = 0; h < 2; ++h) {
      const float4* p = (const float4*)(zr + h * 32 + quad * 8);
      float4 q0 = p[0], q1 = p[1];
      float xs[8] = {q0.x, q0.y, q0.z, q0.w, q1.x, q1.y, q1.z, q1.w};
      half8 ah, al;
#pragma unroll
      for (int e = 0; e < 8; ++e) {
        _Float16 hi = (_Float16)xs[e];
        ah[e] = hi;
        al[e] = (_Float16)(xs[e] - (float)hi);
      }
      afh[h] = ah; afl[h] = al;
    }
  }

  float b1[4], b2[4]; int i1[4];
#pragma unroll
  for (int r = 0; r < 4; ++r) { b1[r] = FLT_MAX; b2[r] = FLT_MAX; i1[r] = 0; }

  for (int phase = 0; phase < 16; ++phase) {
    __syncthreads();  // previous compute done before LDS overwrite
    // ---- stage 64 codewords (hi+lo, 16 KiB): 1024 x 16B over 256 threads ----
#pragma unroll
    for (int i = 0; i < 4; ++i) {
      const int idx   = i * 256 + tid;
      const int seg   = idx >> 6;       // 0..15 (0..7 hi, 8..15 lo)
      const int off   = idx & 63;
      const int chunk = seg & 7;
      const _Float16* srcb = (seg < 8) ? wsH : wsL;
      const half8 v = *(const half8*)&srcb[((size_t)chunk * V + phase * 64 + off) * 8];
      if (seg < 8) *(half8*)&sBh[chunk][off][0] = v;
      else         *(half8*)&sBl[chunk][off][0] = v;
    }
    if (tid < 16) {
      float4 q = ((const float4*)(c2g + phase * 64))[tid];
      *(float4*)&sC2[tid * 4] = q;
    }
    __syncthreads();
    // ---- 4 col-tiles of 16 codewords each ----
#pragma unroll 2
    for (int tl = 0; tl < 4; ++tl) {
      const int cwl  = tl * 16 + l15;
      const int vcol = phase * 64 + cwl;
      const float c2v = sC2[cwl];
      half8 bh0 = *(const half8*)&sBh[quad][cwl][0];      // k = quad*8+j
      half8 bh1 = *(const half8*)&sBh[4 + quad][cwl][0];  // k = 32+quad*8+j
      half8 bl0 = *(const half8*)&sBl[quad][cwl][0];
      half8 bl1 = *(const half8*)&sBl[4 + quad][cwl][0];
      f32x4 acc = {0.f, 0.f, 0.f, 0.f};
      acc = __builtin_amdgcn_mfma_f32_16x16x32_f16(afh[0], bh0, acc, 0, 0, 0);
      acc = __builtin_amdgcn_mfma_f32_16x16x32_f16(afh[1], bh1, acc, 0, 0, 0);
      acc = __builtin_amdgcn_mfma_f32_16x16x32_f16(afh[0], bl0, acc, 0, 0, 0);
      acc = __builtin_amdgcn_mfma_f32_16x16x32_f16(afh[1], bl1, acc, 0, 0, 0);
      acc = __builtin_amdgcn_mfma_f32_16x16x32_f16(afl[0], bh0, acc, 0, 0, 0);
      acc = __builtin_amdgcn_mfma_f32_16x16x32_f16(afl[1], bh1, acc, 0, 0, 0);
#pragma unroll
      for (int r = 0; r < 4; ++r) {
        float m0 = fmaf(-2.f, acc[r], c2v);
        bool  c0 = m0 < b1[r];
        b2[r] = fminf(b2[r], fmaxf(m0, b1[r]));
        b1[r] = c0 ? m0 : b1[r];
        i1[r] = c0 ? vcol : i1[r];
      }
    }
  }

  // ---- reduce over the 16 col-lanes of each quad group (C: row=quad*4+r, col=l15) ----
#pragma unroll
  for (int r = 0; r < 4; ++r) {
    float v1 = b1[r], v2 = b2[r]; int ix = i1[r];
#pragma unroll
    for (int s = 1; s < 16; s <<= 1) {
      float ov1 = __shfl_xor(v1, s);
      float ov2 = __shfl_xor(v2, s);
      int   oix = __shfl_xor(ix, s);
      bool take = (ov1 < v1) || (ov1 == v1 && oix < ix);  // first-occurrence ties
      float worse = take ? v1 : ov1;
      v2 = fminf(fminf(v2, ov2), worse);
      v1 = take ? ov1 : v1;
      ix = take ? oix : ix;
    }
    b1[r] = v1; b2[r] = v2; i1[r] = ix;
  }

  if (l15 == 0) {
#pragma unroll
    for (int r = 0; r < 4; ++r) {
      int rl = quad * 4 + r;              // row within wave tile
      sW[wv][rl] = i1[r];
      if (b2[r] - b1[r] < MARGIN) {
        int s = atomicAdd(&sFlagCnt, 1);
        sFlagRows[s] = rowbase + rl;      // global row
      }
    }
  }
  __syncthreads();
  if (tid == 0 && sFlagCnt > 0) sFlagBase = atomicAdd(cnt, sFlagCnt);
  __syncthreads();
  if (tid < sFlagCnt) list[sFlagBase + tid] = sFlagRows[tid];

  // tokens (as float): 64 rows per block
  if (tid < 64) tok[blockIdx.x * 64 + tid] = (float)sW[tid >> 4][tid & 15];

  // zq gather: 64 rows x 16 chunks of 16B = 1024 float4 over 256 threads
#pragma unroll
  for (int i = 0; i < 4; ++i) {
    int cid = i * 256 + tid;
    int r = cid >> 4, seg = cid & 15;
    int widx = sW[r >> 4][r & 15];
    float4 val = *(const float4*)(cb + (size_t)widx * D + seg * 4);
    *(float4*)(zq + (size_t)(blockIdx.x * 64 + r) * D + seg * 4) = val;
  }
}

// ---------------- exact fp32 fallback: VERBATIM round-2 block-per-row (proven) ----------------
__global__ __launch_bounds__(256) void vq_fallback(
    const float* __restrict__ z, const float* __restrict__ cb,
    const int* __restrict__ cnt, const int* __restrict__ list,
    float* __restrict__ zq, float* __restrict__ tok) {
  __shared__ float sv[256];
  __shared__ int   si[256];
  const int t = threadIdx.x;
  const int n = cnt[0];
  for (int it = blockIdx.x; it < n; it += gridDim.x) {
    int row = __builtin_amdgcn_readfirstlane(list[it]);
    const float* zr = z + (size_t)row * D;
    float zreg[D];
#pragma unroll
    for (int i = 0; i < D / 4; ++i) {
      float4 q = ((const float4*)zr)[i];
      zreg[4 * i] = q.x; zreg[4 * i + 1] = q.y; zreg[4 * i + 2] = q.z; zreg[4 * i + 3] = q.w;
    }
    float d1 = 0.f;
#pragma unroll
    for (int i = 0; i < D; ++i) d1 = fmaf(zreg[i], zreg[i], d1);
    float best = FLT_MAX; int bidx = 0;
    for (int c = 0; c < 4; ++c) {
      int v = t + 256 * c;
      const float* cp = cb + (size_t)v * D;
      float acc = 0.f, cc = 0.f;
#pragma unroll
      for (int dd = 0; dd < D; ++dd) {
        acc = fmaf(zreg[dd], cp[dd], acc);
        cc  = fmaf(cp[dd], cp[dd], cc);
      }
      float dist = (d1 + cc) - 2.f * acc;
      if (dist < best) { best = dist; bidx = v; }
    }
    sv[t] = best; si[t] = bidx;
    __syncthreads();
    for (int s = 128; s > 0; s >>= 1) {
      if (t < s) {
        float v2 = sv[t + s]; int i2 = si[t + s];
        if (v2 < sv[t] || (v2 == sv[t] && i2 < si[t])) { sv[t] = v2; si[t] = i2; }
      }
      __syncthreads();
    }
    int win = si[0];
    if (t == 0) tok[row] = (float)win;
    if (t < 16) {
      float4 q = ((const float4*)(cb + (size_t)win * D))[t];
      ((float4*)(zq + (size_t)row * D))[t] = q;
    }
    __syncthreads();  // sv/si reused next iteration
  }
}

extern "C" void kernel_launch(void* const* d_in, const int* in_sizes, int n_in,
                              void* d_out, int out_size, void* d_ws, size_t ws_size,
                              hipStream_t stream) {
  const float* z  = (const float*)d_in[0];
  const float* cb = (const float*)d_in[1];

  float* out = (float*)d_out;
  float* zq  = out;                      // [NROWS*D]
  float* tok = out + (size_t)NROWS * D;  // [NROWS]
  float* cbo = tok + NROWS;              // [V*D]

  // ws layout (~520 KiB): wsH 128K | wsL 128K | c2 4K | cnt 256B | list 256K
  char* wsb = (char*)d_ws;
  _Float16* wsH  = (_Float16*)(wsb + 0);
  _Float16* wsL  = (_Float16*)(wsb + 131072);
  float*    c2   = (float*)(wsb + 262144);
  int*      cnt  = (int*)(wsb + 266240);
  int*      list = (int*)(wsb + 266496);

  hipMemsetAsync(cnt, 0, sizeof(int), stream);
  vq_prep<<<V / 256, 256, 0, stream>>>(cb, wsH, wsL, c2, cbo);
  vq_screen<<<1024, 256, 0, stream>>>(z, cb, wsH, wsL, c2, zq, tok, cnt, list);
  vq_fallback<<<1024, 256, 0, stream>>>(z, cb, cnt, list, zq, tok);
}